// Round 5
// baseline (578.584 us; speedup 1.0000x reference)
//
#include <hip/hip_runtime.h>

typedef unsigned short u16;
typedef unsigned int   u32;

#define N_NODES 100000
#define CHUNK_E 8192

typedef short frag8 __attribute__((ext_vector_type(8)));
typedef float f32x4 __attribute__((ext_vector_type(4)));
typedef float f32x2 __attribute__((ext_vector_type(2)));
typedef u32   u32x4 __attribute__((ext_vector_type(4)));

template <typename T>
__device__ __forceinline__ T ntload(const T* p) { return __builtin_nontemporal_load(p); }
template <typename T>
__device__ __forceinline__ void ntstore(T v, T* p) { __builtin_nontemporal_store(v, p); }

__device__ __forceinline__ float bf2f(u16 h) {
    union { u32 u; float f; } c; c.u = ((u32)h) << 16; return c.f;
}
__device__ __forceinline__ u16 f2bf(float f) {
    union { float f; u32 u; } c; c.f = f;
    u32 u = c.u;
    return (u16)((u + 0x7FFFu + ((u >> 16) & 1u)) >> 16);
}
__device__ __forceinline__ float2 bfx2(u32 u) {
    union { u32 u; float f; } lo, hi;
    lo.u = u << 16; hi.u = u & 0xFFFF0000u;
    return make_float2(lo.f, hi.f);
}
__device__ __forceinline__ u32 packbf(float a, float b) {
    return (u32)f2bf(a) | ((u32)f2bf(b) << 16);
}

union U8 { frag8 f; u16 h[8]; };

// ---------------- edge-index layout detect (int32 vs int64) ----------------
__global__ void detect_kernel(const int* __restrict__ ei, int* __restrict__ flag, int E) {
    int any = 0;
    int lim = min(2048, 2 * E);
    for (int i = 1 + 2 * (int)threadIdx.x; i < lim; i += 128) any |= ei[i];
    unsigned long long b = __ballot(any != 0);
    if (threadIdx.x == 0) *flag = (b != 0ULL) ? 1 : 0;  // 1 => int32 layout
}

// ---------------- edge compact: ei (int32/int64) -> int32 srcc, dstc ----------------
__global__ __launch_bounds__(256) void ec_kernel(const int* __restrict__ ei,
                                                 int* __restrict__ srcc,
                                                 int* __restrict__ dstc,
                                                 const int* __restrict__ flag, int E) {
    int e = blockIdx.x * 256 + threadIdx.x;
    if (e >= E) return;
    const int is32 = *flag;
    int s = is32 ? ntload(&ei[e])     : ntload(&ei[2 * (long long)e]);
    int d = is32 ? ntload(&ei[E + e]) : ntload(&ei[2 * (E + (long long)e)]);
    ntstore(s, &srcc[e]);
    ntstore(d, &dstc[e]);
}

// ---------------- CSR build (XCD-partitioned: block b -> chunk b>>3, xcd b&7) ------
// Only edges with (dst>>12)&7 == xcd are handled by this block, so all atomics /
// csr-line writes for a given dst come from one XCD. Edge streams are non-temporal
// so they don't evict the partially-filled csr/cnt lines from that XCD's L2.
__global__ __launch_bounds__(256) void hist_kernel(const int* __restrict__ dstc,
                                                   int* __restrict__ cnt, int E) {
    const int xcd = blockIdx.x & 7;
    const int base = (blockIdx.x >> 3) * CHUNK_E;
    for (int i = 0; i < CHUNK_E; i += 256) {
        int e = base + i + threadIdx.x;
        if (e < E) {
            int d = ntload(&dstc[e]);
            if ((u32)d < (u32)N_NODES && ((d >> 12) & 7) == xcd)
                atomicAdd(&cnt[d], 1);
        }
    }
}

__global__ void scan1_kernel(const int* __restrict__ cnt, int* __restrict__ row,
                             int* __restrict__ part, int n) {
    __shared__ int lds[1024];
    int t = threadIdx.x, g = blockIdx.x * 1024 + t;
    int v = (g < n) ? cnt[g] : 0;
    lds[t] = v;
    __syncthreads();
    for (int off = 1; off < 1024; off <<= 1) {
        int x = (t >= off) ? lds[t - off] : 0;
        __syncthreads();
        lds[t] += x;
        __syncthreads();
    }
    if (g < n) row[g] = lds[t] - v;           // exclusive
    if (t == 1023) part[blockIdx.x] = lds[t]; // block total
}

__global__ void scan2_kernel(int* __restrict__ part, int nb) {
    __shared__ int lds[1024];
    int t = threadIdx.x;
    int v = (t < nb) ? part[t] : 0;
    lds[t] = v;
    __syncthreads();
    for (int off = 1; off < 1024; off <<= 1) {
        int x = (t >= off) ? lds[t - off] : 0;
        __syncthreads();
        lds[t] += x;
        __syncthreads();
    }
    if (t < nb) part[t] = lds[t] - v;
}

__global__ void scan3_kernel(int* __restrict__ row, const int* __restrict__ part,
                             int n, int E) {
    int g = blockIdx.x * 1024 + threadIdx.x;
    if (g < n) row[g] += part[blockIdx.x];
    if (g == 0) row[n] = E;
}

// uses cnt as the fill counter (atomicSub); cnt ends at 0 (re-memset next launch)
__global__ __launch_bounds__(256) void scatter_kernel(const int* __restrict__ srcc,
                                                      const int* __restrict__ dstc,
                                                      const int* __restrict__ row,
                                                      int* __restrict__ cnt,
                                                      int* __restrict__ csr, int E) {
    const int xcd = blockIdx.x & 7;
    const int base = (blockIdx.x >> 3) * CHUNK_E;
    for (int i = 0; i < CHUNK_E; i += 256) {
        int e = base + i + threadIdx.x;
        if (e < E) {
            int d = ntload(&dstc[e]);
            if ((u32)d < (u32)N_NODES && ((d >> 12) & 7) == xcd) {
                int s = ntload(&srcc[e]);
                int idx = atomicSub(&cnt[d], 1) - 1;
                csr[row[d] + idx] = ((u32)s < (u32)N_NODES) ? s : 0;  // cached store
            }
        }
    }
}

// ---------------- weight split: W(fp32) -> bf16 hi + bf16 lo planes ----------------
__global__ void wsplit_kernel(const float* __restrict__ W, u16* __restrict__ hi,
                              u16* __restrict__ lo, int n) {
    int i = blockIdx.x * 256 + threadIdx.x;
    if (i >= n) return;
    float v = W[i];
    u16 h = f2bf(v);
    hi[i] = h;
    lo[i] = f2bf(v - bf2f(h));
}

// ---------------- x -> bf16 hi plane (gather source) ----------------
__global__ void xtobf_kernel(const float* __restrict__ X, u16* __restrict__ out, int n2) {
    int i = blockIdx.x * 256 + threadIdx.x;
    if (i >= n2) return;
    f32x2 v = ntload(&((const f32x2*)X)[i]);
    ntstore(packbf(v[0], v[1]), &((u32*)out)[i]);
}

// ---------------- mean aggregation over CSR (bf16 rows -> bf16 mean) ----------------
// Wave = 1 dst node; lane = g*16+l: neighbor slot g (4 in flight), feat slice l (8
// feats via 16B/lane). MODE 0: plain mean. MODE 1: BN affine, deg==0 -> 0.
template <int MODE>
__global__ __launch_bounds__(256) void agg_kernel(
    const u16* __restrict__ X, const int* __restrict__ rowstart,
    const int* __restrict__ csr, u16* __restrict__ out,
    const float* __restrict__ bnp) {
    const int wid = (blockIdx.x * 256 + threadIdx.x) >> 6;
    const int lane = threadIdx.x & 63;
    const int g = lane >> 4;
    const int l = lane & 15;
    if (wid >= N_NODES) return;
    const int s = rowstart[wid];
    const int e = rowstart[wid + 1];
    const int deg = e - s;
    const u32x4* Xv = (const u32x4*)X;  // row = 16 u32x4
    float av[8] = {0.f, 0.f, 0.f, 0.f, 0.f, 0.f, 0.f, 0.f};
    for (int i = s; i < e; i += 4) {
        if (g < e - i) {
            int idx = ntload(&csr[i + g]);
            u32x4 q = Xv[(size_t)idx * 16 + l];  // cached: src rows are reused
            float2 p0 = bfx2(q[0]), p1 = bfx2(q[1]), p2 = bfx2(q[2]), p3 = bfx2(q[3]);
            av[0] += p0.x; av[1] += p0.y; av[2] += p1.x; av[3] += p1.y;
            av[4] += p2.x; av[5] += p2.y; av[6] += p3.x; av[7] += p3.y;
        }
    }
#pragma unroll
    for (int j = 0; j < 8; ++j) {
        av[j] += __shfl_xor(av[j], 16, 64);
        av[j] += __shfl_xor(av[j], 32, 64);
    }
    if (g == 0) {
        const float inv = 1.0f / (float)max(deg, 1);
#pragma unroll
        for (int j = 0; j < 8; ++j) av[j] *= inv;
        if (MODE == 1) {
            if (deg > 0) {
#pragma unroll
                for (int j = 0; j < 8; ++j)
                    av[j] = av[j] * bnp[l * 8 + j] + bnp[128 + l * 8 + j];
            } else {
#pragma unroll
                for (int j = 0; j < 8; ++j) av[j] = 0.f;
            }
        }
        u32x4 o;
        o[0] = packbf(av[0], av[1]); o[1] = packbf(av[2], av[3]);
        o[2] = packbf(av[4], av[5]); o[3] = packbf(av[6], av[7]);
        ntstore(o, &((u32x4*)out)[(size_t)wid * 16 + l]);
    }
}

// ---------------- fused GEMM with 4x weight reuse (MT=4 node tiles / wave) --------
// GM 0 (layer 1): A1=meanbf(bf16), A2=x(fp32, split in VALU), 5 MFMAs/step,
//                 epilogue: +bias, L2norm, ReLU, BN sums, write bf16 hi plane (rhh).
// GM 1 (layer 2): A1=meanbf(bf16), A2=rhh(bf16), W_r pre-scaled by BN (hi/lo),
//                 4 MFMAs/step, epilogue: +bias', L2norm, write fp32 d_out.
template <int GM>
__global__ __launch_bounds__(256, 2) void gemm_kernel(
    const u16* __restrict__ A1bf, const float* __restrict__ A2f,
    const u16* __restrict__ A2b,
    const u16* __restrict__ Wlh, const u16* __restrict__ Wll,
    const u16* __restrict__ Wrh, const u16* __restrict__ Wrl,
    const float* __restrict__ bias, float* __restrict__ outf,
    u16* __restrict__ outb, float* __restrict__ bnsums) {
    __shared__ float tile[4][16 * 132];
    __shared__ float ldsbn[256];
    const int tid = threadIdx.x;
    const int lane = tid & 63;
    const int wv = tid >> 6;
    const int col = lane & 15;
    const int quad = lane >> 4;
    if (GM == 0) ldsbn[tid] = 0.f;
    __syncthreads();

    const int nb0 = blockIdx.x * 256 + wv * 64;
    bool act[4];
    int tbc[4];  // clamped tile base (loads always in-bounds; MFMA on dup rows ok)
#pragma unroll
    for (int mt = 0; mt < 4; ++mt) {
        int tb = nb0 + mt * 16;
        act[mt] = (tb < N_NODES);
        tbc[mt] = act[mt] ? tb : (N_NODES - 16);
    }

    f32x4 acc[4][8];
#pragma unroll
    for (int mt = 0; mt < 4; ++mt)
#pragma unroll
        for (int ft = 0; ft < 8; ++ft) acc[mt][ft] = (f32x4){0.f, 0.f, 0.f, 0.f};

    const int wofs = col * 128 + quad * 8;

#pragma unroll
    for (int ks = 0; ks < 4; ++ks) {
        const int k0 = ks * 32 + quad * 8;
        frag8 a1[4];
        U8 a2h[4], a2l[4];
#pragma unroll
        for (int mt = 0; mt < 4; ++mt) {
            const int arow = tbc[mt] + col;
            a1[mt] = ntload((const frag8*)(A1bf + (size_t)arow * 128 + k0));
            if (GM == 0) {
                const f32x4* ap = (const f32x4*)(A2f + (size_t)arow * 128 + k0);
                f32x4 q0 = ntload(ap), q1 = ntload(ap + 1);
                float av[8] = {q0[0], q0[1], q0[2], q0[3], q1[0], q1[1], q1[2], q1[3]};
#pragma unroll
                for (int j = 0; j < 8; ++j) {
                    u16 h = f2bf(av[j]);
                    a2h[mt].h[j] = h;
                    a2l[mt].h[j] = f2bf(av[j] - bf2f(h));
                }
            } else {
                a2h[mt].f = ntload((const frag8*)(A2b + (size_t)arow * 128 + k0));
            }
        }
#pragma unroll
        for (int ft = 0; ft < 8; ++ft) {
            const int wo = ft * 2048 + ks * 32 + wofs;
            frag8 blh = *(const frag8*)(Wlh + wo);
            frag8 bll = *(const frag8*)(Wll + wo);
            frag8 brh = *(const frag8*)(Wrh + wo);
            frag8 brl = *(const frag8*)(Wrl + wo);
#pragma unroll
            for (int mt = 0; mt < 4; ++mt) {
                acc[mt][ft] = __builtin_amdgcn_mfma_f32_16x16x32_bf16(a1[mt], blh, acc[mt][ft], 0, 0, 0);
                acc[mt][ft] = __builtin_amdgcn_mfma_f32_16x16x32_bf16(a1[mt], bll, acc[mt][ft], 0, 0, 0);
                acc[mt][ft] = __builtin_amdgcn_mfma_f32_16x16x32_bf16(a2h[mt].f, brh, acc[mt][ft], 0, 0, 0);
                if (GM == 0)
                    acc[mt][ft] = __builtin_amdgcn_mfma_f32_16x16x32_bf16(a2l[mt].f, brh, acc[mt][ft], 0, 0, 0);
                acc[mt][ft] = __builtin_amdgcn_mfma_f32_16x16x32_bf16(a2h[mt].f, brl, acc[mt][ft], 0, 0, 0);
            }
        }
    }

    float bsv[8];
#pragma unroll
    for (int ft = 0; ft < 8; ++ft) bsv[ft] = bias[ft * 16 + col];

#pragma unroll
    for (int mt = 0; mt < 4; ++mt) {
        if (!act[mt]) continue;  // wave-uniform
        float ss[4] = {0.f, 0.f, 0.f, 0.f};
#pragma unroll
        for (int ft = 0; ft < 8; ++ft)
#pragma unroll
            for (int r = 0; r < 4; ++r) {
                float t = acc[mt][ft][r] + bsv[ft];
                acc[mt][ft][r] = t;
                ss[r] += t * t;
            }
#pragma unroll
        for (int m = 1; m <= 8; m <<= 1)
#pragma unroll
            for (int r = 0; r < 4; ++r) ss[r] += __shfl_xor(ss[r], m, 64);
        float invn[4];
#pragma unroll
        for (int r = 0; r < 4; ++r) invn[r] = 1.0f / fmaxf(sqrtf(ss[r]), 1e-12f);
#pragma unroll
        for (int ft = 0; ft < 8; ++ft)
#pragma unroll
            for (int r = 0; r < 4; ++r) {
                float t = acc[mt][ft][r] * invn[r];
                if (GM == 0) t = fmaxf(t, 0.f);
                acc[mt][ft][r] = t;
                tile[wv][(quad * 4 + r) * 132 + ft * 16 + col] = t;
            }
        if (GM == 0) {
#pragma unroll
            for (int ft = 0; ft < 8; ++ft) {
                float s1 = (acc[mt][ft][0] + acc[mt][ft][1]) + (acc[mt][ft][2] + acc[mt][ft][3]);
                float s2 = (acc[mt][ft][0] * acc[mt][ft][0] + acc[mt][ft][1] * acc[mt][ft][1]) +
                           (acc[mt][ft][2] * acc[mt][ft][2] + acc[mt][ft][3] * acc[mt][ft][3]);
                s1 += __shfl_xor(s1, 16, 64); s1 += __shfl_xor(s1, 32, 64);
                s2 += __shfl_xor(s2, 16, 64); s2 += __shfl_xor(s2, 32, 64);
                if (quad == 0) {
                    atomicAdd(&ldsbn[ft * 16 + col], s1);
                    atomicAdd(&ldsbn[128 + ft * 16 + col], s2);
                }
            }
        }
        asm volatile("s_waitcnt lgkmcnt(0)" ::: "memory");
        const int tb = nb0 + mt * 16;
        if (GM == 0) {
            u32* orow = (u32*)outb;
#pragma unroll
            for (int r = 0; r < 16; ++r) {
                float x0 = tile[wv][r * 132 + 2 * lane];
                float x1 = tile[wv][r * 132 + 2 * lane + 1];
                ntstore(packbf(x0, x1), &orow[(size_t)(tb + r) * 64 + lane]);
            }
        } else {
            f32x2* orow = (f32x2*)outf;
#pragma unroll
            for (int r = 0; r < 16; ++r) {
                f32x2 o;
                o[0] = tile[wv][r * 132 + 2 * lane];
                o[1] = tile[wv][r * 132 + 2 * lane + 1];
                ntstore(o, &orow[(size_t)(tb + r) * 64 + lane]);
            }
        }
        asm volatile("s_waitcnt lgkmcnt(0)" ::: "memory");
    }
    if (GM == 0) {
        __syncthreads();
        atomicAdd(&bnsums[tid], ldsbn[tid]);
    }
}

// ---------------- BN finalize: scale/shift from sums ----------------
__global__ void bnfin_kernel(const float* __restrict__ sums, const float* __restrict__ gamma,
                             const float* __restrict__ beta, float* __restrict__ bnp) {
    int f = threadIdx.x;
    if (f >= 128) return;
    const float invN = 1.0f / (float)N_NODES;
    float mu = sums[f] * invN;
    float var = sums[128 + f] * invN - mu * mu;
    float sc = gamma[f] * rsqrtf(fmaxf(var, 0.f) + 1e-5f);
    bnp[f] = sc;
    bnp[128 + f] = beta[f] - mu * sc;
}

// ---------------- layer-2 weight prep: Wr2' = s .* Wr2 (split), bias2' = b + Wr2@t ----
__global__ void wprep_kernel(const float* __restrict__ Wr2, const float* __restrict__ bl2,
                             const float* __restrict__ bnp, u16* __restrict__ wh,
                             u16* __restrict__ wl, float* __restrict__ bias2p) {
    __shared__ float p[2];
    const int f = blockIdx.x;
    const int k = threadIdx.x;  // 128 threads
    float w = Wr2[f * 128 + k];
    float contrib = w * bnp[128 + k];
    float v = w * bnp[k];
    u16 h = f2bf(v);
    wh[f * 128 + k] = h;
    wl[f * 128 + k] = f2bf(v - bf2f(h));
#pragma unroll
    for (int m = 1; m <= 32; m <<= 1) contrib += __shfl_xor(contrib, m, 64);
    if ((k & 63) == 0) p[k >> 6] = contrib;
    __syncthreads();
    if (k == 0) bias2p[f] = bl2[f] + p[0] + p[1];
}

extern "C" void kernel_launch(void* const* d_in, const int* in_sizes, int n_in,
                              void* d_out, int out_size, void* d_ws, size_t ws_size,
                              hipStream_t stream) {
    const int N = N_NODES;
    const int E = in_sizes[1] / 2;

    const float* x     = (const float*)d_in[0];
    const int*   ei    = (const int*)d_in[1];
    const float* Wl1   = (const float*)d_in[2];
    const float* bl1   = (const float*)d_in[3];
    const float* Wr1   = (const float*)d_in[4];
    const float* gamma = (const float*)d_in[5];
    const float* beta  = (const float*)d_in[6];
    const float* Wl2   = (const float*)d_in[7];
    const float* bl2   = (const float*)d_in[8];
    const float* Wr2   = (const float*)d_in[9];
    float* outp = (float*)d_out;

    char* ws = (char*)d_ws;
    size_t off = 0;
    auto alloc = [&](size_t b) { size_t r = off; off += (b + 255) & ~(size_t)255; return r; };
    int*   flag     = (int*)  (ws + alloc(4));
    int*   cnt      = (int*)  (ws + alloc((size_t)N * 4));
    int*   rowstart = (int*)  (ws + alloc((size_t)(N + 1) * 4));
    int*   partials = (int*)  (ws + alloc(4096));
    int*   csr      = (int*)  (ws + alloc((size_t)E * 4));
    int*   srcc     = (int*)  (ws + alloc((size_t)E * 4));
    int*   dstc     = (int*)  (ws + alloc((size_t)E * 4));
    float* bnsums   = (float*)(ws + alloc(256 * 4));
    float* bnp      = (float*)(ws + alloc(256 * 4));
    float* bias2p   = (float*)(ws + alloc(128 * 4));
    u16*   w1lh     = (u16*)  (ws + alloc(16384 * 2));
    u16*   w1ll     = (u16*)  (ws + alloc(16384 * 2));
    u16*   w1rh     = (u16*)  (ws + alloc(16384 * 2));
    u16*   w1rl     = (u16*)  (ws + alloc(16384 * 2));
    u16*   w2lh     = (u16*)  (ws + alloc(16384 * 2));
    u16*   w2ll     = (u16*)  (ws + alloc(16384 * 2));
    u16*   w2rsh    = (u16*)  (ws + alloc(16384 * 2));
    u16*   w2rsl    = (u16*)  (ws + alloc(16384 * 2));
    u16*   xh       = (u16*)  (ws + alloc((size_t)N * 128 * 2));
    u16*   meanbf   = (u16*)  (ws + alloc((size_t)N * 128 * 2));
    u16*   rhh      = (u16*)  (ws + alloc((size_t)N * 128 * 2));  // ~98 MB total

    hipMemsetAsync(cnt, 0, (size_t)N * 4, stream);
    hipMemsetAsync(bnsums, 0, 256 * 4, stream);

    const int echunks = (E + CHUNK_E - 1) / CHUNK_E;
    detect_kernel<<<1, 64, 0, stream>>>(ei, flag, E);
    ec_kernel<<<(E + 255) / 256, 256, 0, stream>>>(ei, srcc, dstc, flag, E);
    hist_kernel<<<echunks * 8, 256, 0, stream>>>(dstc, cnt, E);
    const int nb = (N + 1023) / 1024;
    scan1_kernel<<<nb, 1024, 0, stream>>>(cnt, rowstart, partials, N);
    scan2_kernel<<<1, 1024, 0, stream>>>(partials, nb);
    scan3_kernel<<<nb, 1024, 0, stream>>>(rowstart, partials, N, E);
    scatter_kernel<<<echunks * 8, 256, 0, stream>>>(srcc, dstc, rowstart, cnt, csr, E);

    wsplit_kernel<<<64, 256, 0, stream>>>(Wl1, w1lh, w1ll, 16384);
    wsplit_kernel<<<64, 256, 0, stream>>>(Wr1, w1rh, w1rl, 16384);
    wsplit_kernel<<<64, 256, 0, stream>>>(Wl2, w2lh, w2ll, 16384);
    xtobf_kernel<<<(N * 64 + 255) / 256, 256, 0, stream>>>(x, xh, N * 64);

    // conv1
    agg_kernel<0><<<(N + 3) / 4, 256, 0, stream>>>(xh, rowstart, csr, meanbf, nullptr);
    gemm_kernel<0><<<(N + 255) / 256, 256, 0, stream>>>(meanbf, x, nullptr,
                                                        w1lh, w1ll, w1rh, w1rl,
                                                        bl1, nullptr, rhh, bnsums);
    bnfin_kernel<<<1, 128, 0, stream>>>(bnsums, gamma, beta, bnp);
    wprep_kernel<<<128, 128, 0, stream>>>(Wr2, bl2, bnp, w2rsh, w2rsl, bias2p);
    // conv2
    agg_kernel<1><<<(N + 3) / 4, 256, 0, stream>>>(rhh, rowstart, csr, meanbf, bnp);
    gemm_kernel<1><<<(N + 255) / 256, 256, 0, stream>>>(meanbf, nullptr, rhh,
                                                        w2lh, w2ll, w2rsh, w2rsl,
                                                        bias2p, outp, nullptr, nullptr);
}

// Round 6
// 533.828 us; speedup vs baseline: 1.0838x; 1.0838x over previous
//
#include <hip/hip_runtime.h>

typedef unsigned short u16;
typedef unsigned int   u32;

#define N_NODES 100000
#define CHUNK_E 8192

typedef short frag8 __attribute__((ext_vector_type(8)));
typedef float f32x4 __attribute__((ext_vector_type(4)));
typedef float f32x2 __attribute__((ext_vector_type(2)));
typedef u32   u32x4 __attribute__((ext_vector_type(4)));

template <typename T>
__device__ __forceinline__ T ntload(const T* p) { return __builtin_nontemporal_load(p); }
template <typename T>
__device__ __forceinline__ void ntstore(T v, T* p) { __builtin_nontemporal_store(v, p); }

__device__ __forceinline__ float bf2f(u16 h) {
    union { u32 u; float f; } c; c.u = ((u32)h) << 16; return c.f;
}
__device__ __forceinline__ u16 f2bf(float f) {
    union { float f; u32 u; } c; c.f = f;
    u32 u = c.u;
    return (u16)((u + 0x7FFFu + ((u >> 16) & 1u)) >> 16);
}
__device__ __forceinline__ float2 bfx2(u32 u) {
    union { u32 u; float f; } lo, hi;
    lo.u = u << 16; hi.u = u & 0xFFFF0000u;
    return make_float2(lo.f, hi.f);
}
__device__ __forceinline__ u32 packbf(float a, float b) {
    return (u32)f2bf(a) | ((u32)f2bf(b) << 16);
}
__device__ __forceinline__ void accum8(float* av, u32x4 q) {
    float2 p0 = bfx2(q[0]), p1 = bfx2(q[1]), p2 = bfx2(q[2]), p3 = bfx2(q[3]);
    av[0] += p0.x; av[1] += p0.y; av[2] += p1.x; av[3] += p1.y;
    av[4] += p2.x; av[5] += p2.y; av[6] += p3.x; av[7] += p3.y;
}

union U8 { frag8 f; u16 h[8]; };

// ---------------- edge-index layout detect (int32 vs int64) ----------------
__global__ void detect_kernel(const int* __restrict__ ei, int* __restrict__ flag, int E) {
    int any = 0;
    int lim = min(2048, 2 * E);
    for (int i = 1 + 2 * (int)threadIdx.x; i < lim; i += 128) any |= ei[i];
    unsigned long long b = __ballot(any != 0);
    if (threadIdx.x == 0) *flag = (b != 0ULL) ? 1 : 0;  // 1 => int32 layout
}

// ---------------- edge compact: ei (int32/int64) -> int32 srcc, dstc ----------------
__global__ __launch_bounds__(256) void ec_kernel(const int* __restrict__ ei,
                                                 int* __restrict__ srcc,
                                                 int* __restrict__ dstc,
                                                 const int* __restrict__ flag, int E) {
    int e = blockIdx.x * 256 + threadIdx.x;
    if (e >= E) return;
    const int is32 = *flag;
    int s = is32 ? ntload(&ei[e])     : ntload(&ei[2 * (long long)e]);
    int d = is32 ? ntload(&ei[E + e]) : ntload(&ei[2 * (E + (long long)e)]);
    ntstore(s, &srcc[e]);
    ntstore(d, &dstc[e]);
}

// ---------------- CSR build (XCD-partitioned: block b -> chunk b>>3, xcd b&7) ------
// Only edges with (dst>>12)&7 == xcd are handled by this block, so all atomics /
// csr-line writes for a given dst come from one XCD. Edge streams are non-temporal
// so they don't evict the partially-filled csr/cnt lines from that XCD's L2.
__global__ __launch_bounds__(256) void hist_kernel(const int* __restrict__ dstc,
                                                   int* __restrict__ cnt, int E) {
    const int xcd = blockIdx.x & 7;
    const int base = (blockIdx.x >> 3) * CHUNK_E;
    for (int i = 0; i < CHUNK_E; i += 256) {
        int e = base + i + threadIdx.x;
        if (e < E) {
            int d = ntload(&dstc[e]);
            if ((u32)d < (u32)N_NODES && ((d >> 12) & 7) == xcd)
                atomicAdd(&cnt[d], 1);
        }
    }
}

__global__ void scan1_kernel(const int* __restrict__ cnt, int* __restrict__ row,
                             int* __restrict__ part, int n) {
    __shared__ int lds[1024];
    int t = threadIdx.x, g = blockIdx.x * 1024 + t;
    int v = (g < n) ? cnt[g] : 0;
    lds[t] = v;
    __syncthreads();
    for (int off = 1; off < 1024; off <<= 1) {
        int x = (t >= off) ? lds[t - off] : 0;
        __syncthreads();
        lds[t] += x;
        __syncthreads();
    }
    if (g < n) row[g] = lds[t] - v;           // exclusive
    if (t == 1023) part[blockIdx.x] = lds[t]; // block total
}

__global__ void scan2_kernel(int* __restrict__ part, int nb) {
    __shared__ int lds[1024];
    int t = threadIdx.x;
    int v = (t < nb) ? part[t] : 0;
    lds[t] = v;
    __syncthreads();
    for (int off = 1; off < 1024; off <<= 1) {
        int x = (t >= off) ? lds[t - off] : 0;
        __syncthreads();
        lds[t] += x;
        __syncthreads();
    }
    if (t < nb) part[t] = lds[t] - v;
}

__global__ void scan3_kernel(int* __restrict__ row, const int* __restrict__ part,
                             int n, int E) {
    int g = blockIdx.x * 1024 + threadIdx.x;
    if (g < n) row[g] += part[blockIdx.x];
    if (g == 0) row[n] = E;
}

// uses cnt as the fill counter (atomicSub); cnt ends at 0 (re-memset next launch)
__global__ __launch_bounds__(256) void scatter_kernel(const int* __restrict__ srcc,
                                                      const int* __restrict__ dstc,
                                                      const int* __restrict__ row,
                                                      int* __restrict__ cnt,
                                                      int* __restrict__ csr, int E) {
    const int xcd = blockIdx.x & 7;
    const int base = (blockIdx.x >> 3) * CHUNK_E;
    for (int i = 0; i < CHUNK_E; i += 256) {
        int e = base + i + threadIdx.x;
        if (e < E) {
            int d = ntload(&dstc[e]);
            if ((u32)d < (u32)N_NODES && ((d >> 12) & 7) == xcd) {
                int s = ntload(&srcc[e]);
                int idx = atomicSub(&cnt[d], 1) - 1;
                csr[row[d] + idx] = ((u32)s < (u32)N_NODES) ? s : 0;  // cached store
            }
        }
    }
}

// ---------------- weight split: W(fp32) -> bf16 hi + bf16 lo planes ----------------
__global__ void wsplit_kernel(const float* __restrict__ W, u16* __restrict__ hi,
                              u16* __restrict__ lo, int n) {
    int i = blockIdx.x * 256 + threadIdx.x;
    if (i >= n) return;
    float v = W[i];
    u16 h = f2bf(v);
    hi[i] = h;
    lo[i] = f2bf(v - bf2f(h));
}

// ---------------- x -> bf16 hi plane (gather source; cached store: agg1 re-reads) ----
__global__ void xtobf_kernel(const float* __restrict__ X, u16* __restrict__ out, int n2) {
    int i = blockIdx.x * 256 + threadIdx.x;
    if (i >= n2) return;
    f32x2 v = ntload(&((const f32x2*)X)[i]);
    ((u32*)out)[i] = packbf(v[0], v[1]);
}

// ---------------- mean aggregation over CSR (bf16 rows -> bf16 mean) ----------------
// Wave = 1 dst node. Up to 64 neighbor indices are loaded into a register with ONE
// coalesced csr read, then distributed by __shfl (register, no memory dependency),
// so the 16B row loads are unconditional straight-line code the compiler can
// software-pipeline (guard-free body; predication only in the <4 tail).
// lane = g*16+l: neighbor slot g, feat slice l. MODE 1: BN affine, deg==0 -> 0.
template <int MODE>
__global__ __launch_bounds__(256) void agg_kernel(
    const u16* __restrict__ X, const int* __restrict__ rowstart,
    const int* __restrict__ csr, u16* __restrict__ out,
    const float* __restrict__ bnp) {
    const int wid = (blockIdx.x * 256 + threadIdx.x) >> 6;
    const int lane = threadIdx.x & 63;
    const int g = lane >> 4;
    const int l = lane & 15;
    if (wid >= N_NODES) return;
    const int s = rowstart[wid];
    const int deg = rowstart[wid + 1] - s;
    const u32x4* Xv = (const u32x4*)X;  // row = 16 u32x4
    float av[8] = {0.f, 0.f, 0.f, 0.f, 0.f, 0.f, 0.f, 0.f};
    for (int base = 0; base < deg; base += 64) {
        const int nb = min(deg - base, 64);
        const int myidx = csr[s + base + min(lane, nb - 1)];  // one coalesced load
        int c = 0;
#pragma unroll 4
        for (; c + 4 <= nb; c += 4) {
            const int idx = __shfl(myidx, c + g, 64);
            u32x4 q = Xv[(size_t)idx * 16 + l];
            accum8(av, q);
        }
        if (c < nb) {  // tail: 1..3 neighbors
            const int idx = __shfl(myidx, min(c + g, nb - 1), 64);
            u32x4 q = Xv[(size_t)idx * 16 + l];
            if (c + g < nb) accum8(av, q);
        }
    }
#pragma unroll
    for (int j = 0; j < 8; ++j) {
        av[j] += __shfl_xor(av[j], 16, 64);
        av[j] += __shfl_xor(av[j], 32, 64);
    }
    if (g == 0) {
        const float inv = 1.0f / (float)max(deg, 1);
#pragma unroll
        for (int j = 0; j < 8; ++j) av[j] *= inv;
        if (MODE == 1) {
            if (deg > 0) {
#pragma unroll
                for (int j = 0; j < 8; ++j)
                    av[j] = av[j] * bnp[l * 8 + j] + bnp[128 + l * 8 + j];
            } else {
#pragma unroll
                for (int j = 0; j < 8; ++j) av[j] = 0.f;
            }
        }
        u32x4 o;
        o[0] = packbf(av[0], av[1]); o[1] = packbf(av[2], av[3]);
        o[2] = packbf(av[4], av[5]); o[3] = packbf(av[6], av[7]);
        ((u32x4*)out)[(size_t)wid * 16 + l] = o;  // cached: consumed by gemm
    }
}

// ---------------- fused GEMM with 4x weight reuse (MT=4 node tiles / wave) --------
// GM 0 (layer 1): A1=meanbf(bf16), A2=x(fp32, split in VALU), 5 MFMAs/step,
//                 epilogue: +bias, L2norm, ReLU, BN sums, write bf16 hi plane (rhh).
// GM 1 (layer 2): A1=meanbf(bf16), A2=rhh(bf16), W_r pre-scaled by BN (hi/lo),
//                 4 MFMAs/step, epilogue: +bias', L2norm, write fp32 d_out.
template <int GM>
__global__ __launch_bounds__(256, 2) void gemm_kernel(
    const u16* __restrict__ A1bf, const float* __restrict__ A2f,
    const u16* __restrict__ A2b,
    const u16* __restrict__ Wlh, const u16* __restrict__ Wll,
    const u16* __restrict__ Wrh, const u16* __restrict__ Wrl,
    const float* __restrict__ bias, float* __restrict__ outf,
    u16* __restrict__ outb, float* __restrict__ bnsums) {
    __shared__ float tile[4][16 * 132];
    __shared__ float ldsbn[256];
    const int tid = threadIdx.x;
    const int lane = tid & 63;
    const int wv = tid >> 6;
    const int col = lane & 15;
    const int quad = lane >> 4;
    if (GM == 0) ldsbn[tid] = 0.f;
    __syncthreads();

    const int nb0 = blockIdx.x * 256 + wv * 64;
    bool act[4];
    int tbc[4];  // clamped tile base (loads always in-bounds; MFMA on dup rows ok)
#pragma unroll
    for (int mt = 0; mt < 4; ++mt) {
        int tb = nb0 + mt * 16;
        act[mt] = (tb < N_NODES);
        tbc[mt] = act[mt] ? tb : (N_NODES - 16);
    }

    f32x4 acc[4][8];
#pragma unroll
    for (int mt = 0; mt < 4; ++mt)
#pragma unroll
        for (int ft = 0; ft < 8; ++ft) acc[mt][ft] = (f32x4){0.f, 0.f, 0.f, 0.f};

    const int wofs = col * 128 + quad * 8;

#pragma unroll
    for (int ks = 0; ks < 4; ++ks) {
        const int k0 = ks * 32 + quad * 8;
        frag8 a1[4];
        U8 a2h[4], a2l[4];
#pragma unroll
        for (int mt = 0; mt < 4; ++mt) {
            const int arow = tbc[mt] + col;
            a1[mt] = ntload((const frag8*)(A1bf + (size_t)arow * 128 + k0));
            if (GM == 0) {
                const f32x4* ap = (const f32x4*)(A2f + (size_t)arow * 128 + k0);
                f32x4 q0 = ntload(ap), q1 = ntload(ap + 1);
                float av[8] = {q0[0], q0[1], q0[2], q0[3], q1[0], q1[1], q1[2], q1[3]};
#pragma unroll
                for (int j = 0; j < 8; ++j) {
                    u16 h = f2bf(av[j]);
                    a2h[mt].h[j] = h;
                    a2l[mt].h[j] = f2bf(av[j] - bf2f(h));
                }
            } else {
                a2h[mt].f = ntload((const frag8*)(A2b + (size_t)arow * 128 + k0));
            }
        }
#pragma unroll
        for (int ft = 0; ft < 8; ++ft) {
            const int wo = ft * 2048 + ks * 32 + wofs;
            frag8 blh = *(const frag8*)(Wlh + wo);
            frag8 bll = *(const frag8*)(Wll + wo);
            frag8 brh = *(const frag8*)(Wrh + wo);
            frag8 brl = *(const frag8*)(Wrl + wo);
#pragma unroll
            for (int mt = 0; mt < 4; ++mt) {
                acc[mt][ft] = __builtin_amdgcn_mfma_f32_16x16x32_bf16(a1[mt], blh, acc[mt][ft], 0, 0, 0);
                acc[mt][ft] = __builtin_amdgcn_mfma_f32_16x16x32_bf16(a1[mt], bll, acc[mt][ft], 0, 0, 0);
                acc[mt][ft] = __builtin_amdgcn_mfma_f32_16x16x32_bf16(a2h[mt].f, brh, acc[mt][ft], 0, 0, 0);
                if (GM == 0)
                    acc[mt][ft] = __builtin_amdgcn_mfma_f32_16x16x32_bf16(a2l[mt].f, brh, acc[mt][ft], 0, 0, 0);
                acc[mt][ft] = __builtin_amdgcn_mfma_f32_16x16x32_bf16(a2h[mt].f, brl, acc[mt][ft], 0, 0, 0);
            }
        }
    }

    float bsv[8];
#pragma unroll
    for (int ft = 0; ft < 8; ++ft) bsv[ft] = bias[ft * 16 + col];

#pragma unroll
    for (int mt = 0; mt < 4; ++mt) {
        if (!act[mt]) continue;  // wave-uniform
        float ss[4] = {0.f, 0.f, 0.f, 0.f};
#pragma unroll
        for (int ft = 0; ft < 8; ++ft)
#pragma unroll
            for (int r = 0; r < 4; ++r) {
                float t = acc[mt][ft][r] + bsv[ft];
                acc[mt][ft][r] = t;
                ss[r] += t * t;
            }
#pragma unroll
        for (int m = 1; m <= 8; m <<= 1)
#pragma unroll
            for (int r = 0; r < 4; ++r) ss[r] += __shfl_xor(ss[r], m, 64);
        float invn[4];
#pragma unroll
        for (int r = 0; r < 4; ++r) invn[r] = 1.0f / fmaxf(sqrtf(ss[r]), 1e-12f);
#pragma unroll
        for (int ft = 0; ft < 8; ++ft)
#pragma unroll
            for (int r = 0; r < 4; ++r) {
                float t = acc[mt][ft][r] * invn[r];
                if (GM == 0) t = fmaxf(t, 0.f);
                acc[mt][ft][r] = t;
                tile[wv][(quad * 4 + r) * 132 + ft * 16 + col] = t;
            }
        if (GM == 0) {
#pragma unroll
            for (int ft = 0; ft < 8; ++ft) {
                float s1 = (acc[mt][ft][0] + acc[mt][ft][1]) + (acc[mt][ft][2] + acc[mt][ft][3]);
                float s2 = (acc[mt][ft][0] * acc[mt][ft][0] + acc[mt][ft][1] * acc[mt][ft][1]) +
                           (acc[mt][ft][2] * acc[mt][ft][2] + acc[mt][ft][3] * acc[mt][ft][3]);
                s1 += __shfl_xor(s1, 16, 64); s1 += __shfl_xor(s1, 32, 64);
                s2 += __shfl_xor(s2, 16, 64); s2 += __shfl_xor(s2, 32, 64);
                if (quad == 0) {
                    atomicAdd(&ldsbn[ft * 16 + col], s1);
                    atomicAdd(&ldsbn[128 + ft * 16 + col], s2);
                }
            }
        }
        asm volatile("s_waitcnt lgkmcnt(0)" ::: "memory");
        const int tb = nb0 + mt * 16;
        if (GM == 0) {
            u32* orow = (u32*)outb;  // cached: rhh consumed by agg2/gemm2
#pragma unroll
            for (int r = 0; r < 16; ++r) {
                float x0 = tile[wv][r * 132 + 2 * lane];
                float x1 = tile[wv][r * 132 + 2 * lane + 1];
                orow[(size_t)(tb + r) * 64 + lane] = packbf(x0, x1);
            }
        } else {
            f32x2* orow = (f32x2*)outf;  // final output: non-temporal
#pragma unroll
            for (int r = 0; r < 16; ++r) {
                f32x2 o;
                o[0] = tile[wv][r * 132 + 2 * lane];
                o[1] = tile[wv][r * 132 + 2 * lane + 1];
                ntstore(o, &orow[(size_t)(tb + r) * 64 + lane]);
            }
        }
        asm volatile("s_waitcnt lgkmcnt(0)" ::: "memory");
    }
    if (GM == 0) {
        __syncthreads();
        atomicAdd(&bnsums[tid], ldsbn[tid]);
    }
}

// ---------------- BN finalize: scale/shift from sums ----------------
__global__ void bnfin_kernel(const float* __restrict__ sums, const float* __restrict__ gamma,
                             const float* __restrict__ beta, float* __restrict__ bnp) {
    int f = threadIdx.x;
    if (f >= 128) return;
    const float invN = 1.0f / (float)N_NODES;
    float mu = sums[f] * invN;
    float var = sums[128 + f] * invN - mu * mu;
    float sc = gamma[f] * rsqrtf(fmaxf(var, 0.f) + 1e-5f);
    bnp[f] = sc;
    bnp[128 + f] = beta[f] - mu * sc;
}

// ---------------- layer-2 weight prep: Wr2' = s .* Wr2 (split), bias2' = b + Wr2@t ----
__global__ void wprep_kernel(const float* __restrict__ Wr2, const float* __restrict__ bl2,
                             const float* __restrict__ bnp, u16* __restrict__ wh,
                             u16* __restrict__ wl, float* __restrict__ bias2p) {
    __shared__ float p[2];
    const int f = blockIdx.x;
    const int k = threadIdx.x;  // 128 threads
    float w = Wr2[f * 128 + k];
    float contrib = w * bnp[128 + k];
    float v = w * bnp[k];
    u16 h = f2bf(v);
    wh[f * 128 + k] = h;
    wl[f * 128 + k] = f2bf(v - bf2f(h));
#pragma unroll
    for (int m = 1; m <= 32; m <<= 1) contrib += __shfl_xor(contrib, m, 64);
    if ((k & 63) == 0) p[k >> 6] = contrib;
    __syncthreads();
    if (k == 0) bias2p[f] = bl2[f] + p[0] + p[1];
}

extern "C" void kernel_launch(void* const* d_in, const int* in_sizes, int n_in,
                              void* d_out, int out_size, void* d_ws, size_t ws_size,
                              hipStream_t stream) {
    const int N = N_NODES;
    const int E = in_sizes[1] / 2;

    const float* x     = (const float*)d_in[0];
    const int*   ei    = (const int*)d_in[1];
    const float* Wl1   = (const float*)d_in[2];
    const float* bl1   = (const float*)d_in[3];
    const float* Wr1   = (const float*)d_in[4];
    const float* gamma = (const float*)d_in[5];
    const float* beta  = (const float*)d_in[6];
    const float* Wl2   = (const float*)d_in[7];
    const float* bl2   = (const float*)d_in[8];
    const float* Wr2   = (const float*)d_in[9];
    float* outp = (float*)d_out;

    char* ws = (char*)d_ws;
    size_t off = 0;
    auto alloc = [&](size_t b) { size_t r = off; off += (b + 255) & ~(size_t)255; return r; };
    int*   flag     = (int*)  (ws + alloc(4));
    int*   cnt      = (int*)  (ws + alloc((size_t)N * 4));
    int*   rowstart = (int*)  (ws + alloc((size_t)(N + 1) * 4));
    int*   partials = (int*)  (ws + alloc(4096));
    int*   csr      = (int*)  (ws + alloc((size_t)E * 4));
    int*   srcc     = (int*)  (ws + alloc((size_t)E * 4));
    int*   dstc     = (int*)  (ws + alloc((size_t)E * 4));
    float* bnsums   = (float*)(ws + alloc(256 * 4));
    float* bnp      = (float*)(ws + alloc(256 * 4));
    float* bias2p   = (float*)(ws + alloc(128 * 4));
    u16*   w1lh     = (u16*)  (ws + alloc(16384 * 2));
    u16*   w1ll     = (u16*)  (ws + alloc(16384 * 2));
    u16*   w1rh     = (u16*)  (ws + alloc(16384 * 2));
    u16*   w1rl     = (u16*)  (ws + alloc(16384 * 2));
    u16*   w2lh     = (u16*)  (ws + alloc(16384 * 2));
    u16*   w2ll     = (u16*)  (ws + alloc(16384 * 2));
    u16*   w2rsh    = (u16*)  (ws + alloc(16384 * 2));
    u16*   w2rsl    = (u16*)  (ws + alloc(16384 * 2));
    u16*   xh       = (u16*)  (ws + alloc((size_t)N * 128 * 2));
    u16*   meanbf   = (u16*)  (ws + alloc((size_t)N * 128 * 2));
    u16*   rhh      = (u16*)  (ws + alloc((size_t)N * 128 * 2));  // ~98 MB total

    hipMemsetAsync(cnt, 0, (size_t)N * 4, stream);
    hipMemsetAsync(bnsums, 0, 256 * 4, stream);

    const int echunks = (E + CHUNK_E - 1) / CHUNK_E;
    detect_kernel<<<1, 64, 0, stream>>>(ei, flag, E);
    ec_kernel<<<(E + 255) / 256, 256, 0, stream>>>(ei, srcc, dstc, flag, E);
    hist_kernel<<<echunks * 8, 256, 0, stream>>>(dstc, cnt, E);
    const int nb = (N + 1023) / 1024;
    scan1_kernel<<<nb, 1024, 0, stream>>>(cnt, rowstart, partials, N);
    scan2_kernel<<<1, 1024, 0, stream>>>(partials, nb);
    scan3_kernel<<<nb, 1024, 0, stream>>>(rowstart, partials, N, E);
    scatter_kernel<<<echunks * 8, 256, 0, stream>>>(srcc, dstc, rowstart, cnt, csr, E);

    wsplit_kernel<<<64, 256, 0, stream>>>(Wl1, w1lh, w1ll, 16384);
    wsplit_kernel<<<64, 256, 0, stream>>>(Wr1, w1rh, w1rl, 16384);
    wsplit_kernel<<<64, 256, 0, stream>>>(Wl2, w2lh, w2ll, 16384);
    xtobf_kernel<<<(N * 64 + 255) / 256, 256, 0, stream>>>(x, xh, N * 64);

    // conv1
    agg_kernel<0><<<(N + 3) / 4, 256, 0, stream>>>(xh, rowstart, csr, meanbf, nullptr);
    gemm_kernel<0><<<(N + 255) / 256, 256, 0, stream>>>(meanbf, x, nullptr,
                                                        w1lh, w1ll, w1rh, w1rl,
                                                        bl1, nullptr, rhh, bnsums);
    bnfin_kernel<<<1, 128, 0, stream>>>(bnsums, gamma, beta, bnp);
    wprep_kernel<<<128, 128, 0, stream>>>(Wr2, bl2, bnp, w2rsh, w2rsl, bias2p);
    // conv2
    agg_kernel<1><<<(N + 3) / 4, 256, 0, stream>>>(rhh, rowstart, csr, meanbf, bnp);
    gemm_kernel<1><<<(N + 255) / 256, 256, 0, stream>>>(meanbf, nullptr, rhh,
                                                        w2lh, w2ll, w2rsh, w2rsl,
                                                        bias2p, outp, nullptr, nullptr);
}